// Round 6
// baseline (39.891 us; speedup 1.0000x reference)
//
#include <hip/hip_runtime.h>

#define NX 4096
#define NY 2048
#define EPS 1e-8f
#define ROWS 4          // rows per wave strip (short chain; batch fits in VGPRs)
#define CPW 63          // output columns per block
#define INV_D 0.001f

typedef float f32x2 __attribute__((ext_vector_type(2)));

__device__ __forceinline__ int clampi(int i, int lo, int hi) {
    return i < lo ? lo : (i > hi ? hi : i);
}

// Scalar one-rcp WENO5 (leading fn face only).
__device__ __forceinline__ float weno5_s(float qm2, float qm1, float q0,
                                         float qp1, float qp2) {
    float f1 = fmaf(1.0f/3.0f, qm2, fmaf(-7.0f/6.0f, qm1, (11.0f/6.0f)*q0));
    float f2 = fmaf(-1.0f/6.0f, qm1, fmaf(5.0f/6.0f, q0, (1.0f/3.0f)*qp1));
    float f3 = fmaf(1.0f/3.0f, q0, fmaf(5.0f/6.0f, qp1, (-1.0f/6.0f)*qp2));
    const float k1 = 13.0f/12.0f, k2 = 0.25f;
    float d1 = qm2 - 2.0f*qm1 + q0,  e1 = qm2 - 4.0f*qm1 + 3.0f*q0;
    float d2 = qm1 - 2.0f*q0 + qp1,  e2 = qm1 - qp1;
    float d3 = q0 - 2.0f*qp1 + qp2,  e3 = 3.0f*q0 - 4.0f*qp1 + qp2;
    float b1 = fmaf(k1, d1*d1, k2*(e1*e1));
    float b2 = fmaf(k1, d2*d2, k2*(e2*e2));
    float b3 = fmaf(k1, d3*d3, k2*(e3*e3));
    float t1 = b1 + EPS, t2 = b2 + EPS, t3 = b3 + EPS;
    float p23 = t2*t3, p13 = t1*t3, p12 = t1*t2;
    float w1 = 0.1f*(p23*p23), w2 = 0.6f*(p13*p13), w3 = 0.3f*(p12*p12);
    float num = fmaf(w1, f1, fmaf(w2, f2, w3*f3));
    return num * __builtin_amdgcn_rcpf((w1 + w2) + w3);
}

// Packed (2-wide) one-rcp WENO5: .x = fe face, .y = fn face.
__device__ __forceinline__ f32x2 weno5_pk(f32x2 qm2, f32x2 qm1, f32x2 q0,
                                          f32x2 qp1, f32x2 qp2) {
    f32x2 f1 = (1.0f/3.0f)*qm2 - (7.0f/6.0f)*qm1 + (11.0f/6.0f)*q0;
    f32x2 f2 = (-1.0f/6.0f)*qm1 + (5.0f/6.0f)*q0 + (1.0f/3.0f)*qp1;
    f32x2 f3 = (1.0f/3.0f)*q0 + (5.0f/6.0f)*qp1 - (1.0f/6.0f)*qp2;
    f32x2 d1 = qm2 - 2.0f*qm1 + q0;
    f32x2 e1 = qm2 - 4.0f*qm1 + 3.0f*q0;
    f32x2 d2 = qm1 - 2.0f*q0 + qp1;
    f32x2 e2 = qm1 - qp1;
    f32x2 d3 = q0 - 2.0f*qp1 + qp2;
    f32x2 e3 = 3.0f*q0 - 4.0f*qp1 + qp2;
    const float k1 = 13.0f/12.0f, k2 = 0.25f;
    f32x2 b1 = k1*(d1*d1) + k2*(e1*e1);
    f32x2 b2 = k1*(d2*d2) + k2*(e2*e2);
    f32x2 b3 = k1*(d3*d3) + k2*(e3*e3);
    f32x2 t1 = b1 + EPS, t2 = b2 + EPS, t3 = b3 + EPS;
    f32x2 p23 = t2*t3, p13 = t1*t3, p12 = t1*t2;
    f32x2 w1 = 0.1f*(p23*p23);
    f32x2 w2 = 0.6f*(p13*p13);
    f32x2 w3 = 0.3f*(p12*p12);
    f32x2 num = w1*f1 + w2*f2 + w3*f3;
    f32x2 den = (w1 + w2) + w3;
    f32x2 rc;
    rc.x = __builtin_amdgcn_rcpf(den.x);
    rc.y = __builtin_amdgcn_rcpf(den.y);
    return num * rc;
}

// One wave strip: 4 rows x 63 output columns. Phase 1 batches ALL global
// loads (43) into registers -- small enough that the allocator keeps them
// live; phase 2 is pure VALU + one shuffle per row.
template <bool EDGE>
__device__ __forceinline__ void run_strip(const float* __restrict__ h,
                                          const float* __restrict__ u,
                                          const float* __restrict__ v,
                                          float* __restrict__ out,
                                          int x0, int y0w, int lane) {
    const int xf = x0 - 1 + lane;                       // x-face this lane owns
    const int xo = x0 + lane;                           // output column
    const int xc = EDGE ? (xo < NX ? xo : NX - 1) : xo; // column for fn path
    const int xq = EDGE ? clampi(xf, 0, NX - 1) : xf;   // column for u loads

    int xs[6];
    if (EDGE) {
#pragma unroll
        for (int k = 0; k < 6; ++k) xs[k] = clampi(xf - 2 + k, 0, NX - 1);
    }

    // ================= phase 1: batched loads (long-latency first) ========
    float col[ROWS + 6];                 // h column xc, rows y0w-3 .. y0w+6
#pragma unroll
    for (int k = 0; k < ROWS + 6; ++k) {
        int yy = EDGE ? clampi(y0w - 3 + k, 0, NY - 1) : (y0w - 3 + k);
        col[k] = h[(size_t)yy * NX + xc];
    }
    float vv[ROWS + 1];                  // v at face rows y0w-1 .. y0w+3
#pragma unroll
    for (int j = 0; j <= ROWS; ++j) {
        int fy = EDGE ? clampi(y0w - 1 + j, 0, NY - 1) : (y0w - 1 + j);
        vv[j] = v[(size_t)fy * NX + xc];
    }
    float uu[ROWS];                      // u[y][xf]
#pragma unroll
    for (int r = 0; r < ROWS; ++r)
        uu[r] = u[(size_t)(y0w + r) * NX + xq];
    float st[ROWS][6];                   // h[y][xf-2 .. xf+3] per row
#pragma unroll
    for (int r = 0; r < ROWS; ++r) {
        const float* hr = h + (size_t)(y0w + r) * NX;
        if (EDGE) {
#pragma unroll
            for (int k = 0; k < 6; ++k) st[r][k] = hr[xs[k]];
        } else {
#pragma unroll
            for (int k = 0; k < 6; ++k) st[r][k] = hr[xf - 2 + k];
        }
    }

    // ================= phase 2: compute =================
    float fn_prev;
    {
        float vl = vv[0];
        bool vp = (vl >= 0.0f);
        fn_prev = vl * weno5_s(vp ? col[0] : col[5], vp ? col[1] : col[4],
                               vp ? col[2] : col[3], vp ? col[3] : col[2],
                               vp ? col[4] : col[1]);
    }

#pragma unroll
    for (int r = 0; r < ROWS; ++r) {
        const int y = y0w + r;
        float uval = uu[r];
        float vval = vv[r + 1];
        bool up = (uval >= 0.0f);
        bool vp = (vval >= 0.0f);
        f32x2 a = { up ? st[r][0] : st[r][5], vp ? col[r+1] : col[r+6] };
        f32x2 b = { up ? st[r][1] : st[r][4], vp ? col[r+2] : col[r+5] };
        f32x2 c = { up ? st[r][2] : st[r][3], vp ? col[r+3] : col[r+4] };
        f32x2 d = { up ? st[r][3] : st[r][2], vp ? col[r+4] : col[r+3] };
        f32x2 e = { up ? st[r][4] : st[r][1], vp ? col[r+5] : col[r+2] };
        f32x2 q = weno5_pk(a, b, c, d, e);
        float fe = uval * q.x;            // face at column xo-1
        float fn_cur = vval * q.y;        // face at row y
        float fe_r = __shfl_down(fe, 1);  // face at column xo
        float val = ((fe - fe_r) + (fn_prev - fn_cur)) * INV_D;  // = -div

        if (EDGE) {
            if (xo < 2 || xo >= NX - 2 || y < 2 || y >= NY - 2) val = 0.0f;
            if (lane < CPW && xo < NX)
                __builtin_nontemporal_store(val, out + (size_t)y * NX + xo);
        } else {
            if (lane < CPW)
                __builtin_nontemporal_store(val, out + (size_t)y * NX + xo);
        }
        fn_prev = fn_cur;
    }
}

__global__ __launch_bounds__(256) void adv_kernel(const float* __restrict__ h,
                                                  const float* __restrict__ u,
                                                  const float* __restrict__ v,
                                                  float* __restrict__ out) {
    const int lane = threadIdx.x & 63;
    const int wid  = threadIdx.x >> 6;
    const int x0 = blockIdx.x * CPW;
    const int y0w = (blockIdx.y * 4 + wid) * ROWS;

    const bool edge = (blockIdx.x == 0) || (blockIdx.x >= 64) ||
                      (blockIdx.y == 0) || (blockIdx.y == gridDim.y - 1);
    if (edge)
        run_strip<true>(h, u, v, out, x0, y0w, lane);
    else
        run_strip<false>(h, u, v, out, x0, y0w, lane);
}

extern "C" void kernel_launch(void* const* d_in, const int* in_sizes, int n_in,
                              void* d_out, int out_size, void* d_ws, size_t ws_size,
                              hipStream_t stream) {
    const float* h = (const float*)d_in[0];
    const float* u = (const float*)d_in[1];
    const float* v = (const float*)d_in[2];
    float* out = (float*)d_out;

    dim3 block(256, 1, 1);
    dim3 grid((NX + CPW - 1) / CPW, NY / (4 * ROWS), 1);  // 66 x 128
    adv_kernel<<<grid, block, 0, stream>>>(h, u, v, out);
}

// Round 7
// 39.081 us; speedup vs baseline: 1.0207x; 1.0207x over previous
//
#include <hip/hip_runtime.h>

#define NX 4096
#define NY 2048
#define EPS 1e-8f
#define ROWS 8          // rows per wave strip
#define CPW 63          // output columns per block
#define INV_D 0.001f

typedef float f32x2 __attribute__((ext_vector_type(2)));

__device__ __forceinline__ int clampi(int i, int lo, int hi) {
    return i < lo ? lo : (i > hi ? hi : i);
}

// Scalar one-rcp WENO5 (leading fn face only).
__device__ __forceinline__ float weno5_s(float qm2, float qm1, float q0,
                                         float qp1, float qp2) {
    float f1 = fmaf(1.0f/3.0f, qm2, fmaf(-7.0f/6.0f, qm1, (11.0f/6.0f)*q0));
    float f2 = fmaf(-1.0f/6.0f, qm1, fmaf(5.0f/6.0f, q0, (1.0f/3.0f)*qp1));
    float f3 = fmaf(1.0f/3.0f, q0, fmaf(5.0f/6.0f, qp1, (-1.0f/6.0f)*qp2));
    const float k1 = 13.0f/12.0f, k2 = 0.25f;
    float d1 = qm2 - 2.0f*qm1 + q0,  e1 = qm2 - 4.0f*qm1 + 3.0f*q0;
    float d2 = qm1 - 2.0f*q0 + qp1,  e2 = qm1 - qp1;
    float d3 = q0 - 2.0f*qp1 + qp2,  e3 = 3.0f*q0 - 4.0f*qp1 + qp2;
    float b1 = fmaf(k1, d1*d1, k2*(e1*e1));
    float b2 = fmaf(k1, d2*d2, k2*(e2*e2));
    float b3 = fmaf(k1, d3*d3, k2*(e3*e3));
    float t1 = b1 + EPS, t2 = b2 + EPS, t3 = b3 + EPS;
    float p23 = t2*t3, p13 = t1*t3, p12 = t1*t2;
    float w1 = 0.1f*(p23*p23), w2 = 0.6f*(p13*p13), w3 = 0.3f*(p12*p12);
    float num = fmaf(w1, f1, fmaf(w2, f2, w3*f3));
    return num * __builtin_amdgcn_rcpf((w1 + w2) + w3);
}

// Packed (2-wide) one-rcp WENO5: .x = fe face, .y = fn face.
__device__ __forceinline__ f32x2 weno5_pk(f32x2 qm2, f32x2 qm1, f32x2 q0,
                                          f32x2 qp1, f32x2 qp2) {
    f32x2 f1 = (1.0f/3.0f)*qm2 - (7.0f/6.0f)*qm1 + (11.0f/6.0f)*q0;
    f32x2 f2 = (-1.0f/6.0f)*qm1 + (5.0f/6.0f)*q0 + (1.0f/3.0f)*qp1;
    f32x2 f3 = (1.0f/3.0f)*q0 + (5.0f/6.0f)*qp1 - (1.0f/6.0f)*qp2;
    f32x2 d1 = qm2 - 2.0f*qm1 + q0;
    f32x2 e1 = qm2 - 4.0f*qm1 + 3.0f*q0;
    f32x2 d2 = qm1 - 2.0f*q0 + qp1;
    f32x2 e2 = qm1 - qp1;
    f32x2 d3 = q0 - 2.0f*qp1 + qp2;
    f32x2 e3 = 3.0f*q0 - 4.0f*qp1 + qp2;
    const float k1 = 13.0f/12.0f, k2 = 0.25f;
    f32x2 b1 = k1*(d1*d1) + k2*(e1*e1);
    f32x2 b2 = k1*(d2*d2) + k2*(e2*e2);
    f32x2 b3 = k1*(d3*d3) + k2*(e3*e3);
    f32x2 t1 = b1 + EPS, t2 = b2 + EPS, t3 = b3 + EPS;
    f32x2 p23 = t2*t3, p13 = t1*t3, p12 = t1*t2;
    f32x2 w1 = 0.1f*(p23*p23);
    f32x2 w2 = 0.6f*(p13*p13);
    f32x2 w3 = 0.3f*(p12*p12);
    f32x2 num = w1*f1 + w2*f2 + w3*f3;
    f32x2 den = (w1 + w2) + w3;
    f32x2 rc;
    rc.x = __builtin_amdgcn_rcpf(den.x);
    rc.y = __builtin_amdgcn_rcpf(den.y);
    return num * rc;
}

// Interior column accessor: col[k] (k=0..ROWS+5) holds h[y0w-3+k][xc].
// For k=3..ROWS+2 this duplicates st[k-3][3] (same lane: xc == xf+1), so only
// the 3 head / 3 tail values are loaded separately.
#define COLV(k) (EDGE ? colF[(k)] \
                      : ((k) < 3 ? colA[(k)] \
                                 : ((k) < ROWS + 3 ? st[(k)-3][3] \
                                                   : colB[(k)-ROWS-3])))

// One wave strip: 8 rows x 63 output columns. Phase 1 issues ALL global
// loads; sched_barrier(0) forbids the scheduler from sinking them into the
// compute phase, so they stay batched (deep MLP) and live in registers.
template <bool EDGE>
__device__ __forceinline__ void run_strip(const float* __restrict__ h,
                                          const float* __restrict__ u,
                                          const float* __restrict__ v,
                                          float* __restrict__ out,
                                          int x0, int y0w, int lane) {
    const int xf = x0 - 1 + lane;                       // x-face this lane owns
    const int xo = x0 + lane;                           // output column
    const int xc = EDGE ? (xo < NX ? xo : NX - 1) : xo; // column for fn path
    const int xq = EDGE ? clampi(xf, 0, NX - 1) : xf;   // column for u loads

    int xs[6];
    if (EDGE) {
#pragma unroll
        for (int k = 0; k < 6; ++k) xs[k] = clampi(xf - 2 + k, 0, NX - 1);
    }

    // ================= phase 1: batched loads =================
    float colA[3], colB[3], colF[ROWS + 6];
    if (EDGE) {
#pragma unroll
        for (int k = 0; k < ROWS + 6; ++k) {
            int yy = clampi(y0w - 3 + k, 0, NY - 1);
            colF[k] = h[(size_t)yy * NX + xc];
        }
    } else {
#pragma unroll
        for (int k = 0; k < 3; ++k) {
            colA[k] = h[(size_t)(y0w - 3 + k) * NX + xc];
            colB[k] = h[(size_t)(y0w + ROWS + k) * NX + xc];
        }
    }
    float vv[ROWS + 1];                  // v at face rows y0w-1 .. y0w+ROWS-1
#pragma unroll
    for (int j = 0; j <= ROWS; ++j) {
        int fy = EDGE ? clampi(y0w - 1 + j, 0, NY - 1) : (y0w - 1 + j);
        vv[j] = v[(size_t)fy * NX + xc];
    }
    float uu[ROWS];                      // u[y][xf]
#pragma unroll
    for (int r = 0; r < ROWS; ++r)
        uu[r] = u[(size_t)(y0w + r) * NX + xq];
    float st[ROWS][6];                   // h[y][xf-2 .. xf+3] per row
#pragma unroll
    for (int r = 0; r < ROWS; ++r) {
        const float* hr = h + (size_t)(y0w + r) * NX;
        if (EDGE) {
#pragma unroll
            for (int k = 0; k < 6; ++k) st[r][k] = hr[xs[k]];
        } else {
#pragma unroll
            for (int k = 0; k < 6; ++k) st[r][k] = hr[xf - 2 + k];
        }
    }

    // Loads may not sink past this point; compute may not hoist above it.
    __builtin_amdgcn_sched_barrier(0);

    // ================= phase 2: compute =================
    float fn_prev;
    {
        float vl = vv[0];
        bool vp = (vl >= 0.0f);
        fn_prev = vl * weno5_s(vp ? COLV(0) : COLV(5), vp ? COLV(1) : COLV(4),
                               vp ? COLV(2) : COLV(3), vp ? COLV(3) : COLV(2),
                               vp ? COLV(4) : COLV(1));
    }

#pragma unroll
    for (int r = 0; r < ROWS; ++r) {
        const int y = y0w + r;
        float uval = uu[r];
        float vval = vv[r + 1];
        bool up = (uval >= 0.0f);
        bool vp = (vval >= 0.0f);
        f32x2 a = { up ? st[r][0] : st[r][5], vp ? COLV(r+1) : COLV(r+6) };
        f32x2 b = { up ? st[r][1] : st[r][4], vp ? COLV(r+2) : COLV(r+5) };
        f32x2 c = { up ? st[r][2] : st[r][3], vp ? COLV(r+3) : COLV(r+4) };
        f32x2 d = { up ? st[r][3] : st[r][2], vp ? COLV(r+4) : COLV(r+3) };
        f32x2 e = { up ? st[r][4] : st[r][1], vp ? COLV(r+5) : COLV(r+2) };
        f32x2 q = weno5_pk(a, b, c, d, e);
        float fe = uval * q.x;            // face at column xo-1
        float fn_cur = vval * q.y;        // face at row y
        float fe_r = __shfl_down(fe, 1);  // face at column xo
        float val = ((fe - fe_r) + (fn_prev - fn_cur)) * INV_D;  // = -div

        if (EDGE) {
            if (xo < 2 || xo >= NX - 2 || y < 2 || y >= NY - 2) val = 0.0f;
            if (lane < CPW && xo < NX)
                __builtin_nontemporal_store(val, out + (size_t)y * NX + xo);
        } else {
            if (lane < CPW)
                __builtin_nontemporal_store(val, out + (size_t)y * NX + xo);
        }
        fn_prev = fn_cur;
    }
}

__global__ __launch_bounds__(256, 4) void adv_kernel(const float* __restrict__ h,
                                                     const float* __restrict__ u,
                                                     const float* __restrict__ v,
                                                     float* __restrict__ out) {
    const int lane = threadIdx.x & 63;
    const int wid  = threadIdx.x >> 6;
    const int x0 = blockIdx.x * CPW;
    const int y0w = (blockIdx.y * 4 + wid) * ROWS;

    const bool edge = (blockIdx.x == 0) || (blockIdx.x >= 64) ||
                      (blockIdx.y == 0) || (blockIdx.y == gridDim.y - 1);
    if (edge)
        run_strip<true>(h, u, v, out, x0, y0w, lane);
    else
        run_strip<false>(h, u, v, out, x0, y0w, lane);
}

extern "C" void kernel_launch(void* const* d_in, const int* in_sizes, int n_in,
                              void* d_out, int out_size, void* d_ws, size_t ws_size,
                              hipStream_t stream) {
    const float* h = (const float*)d_in[0];
    const float* u = (const float*)d_in[1];
    const float* v = (const float*)d_in[2];
    float* out = (float*)d_out;

    dim3 block(256, 1, 1);
    dim3 grid((NX + CPW - 1) / CPW, NY / (4 * ROWS), 1);  // 66 x 64
    adv_kernel<<<grid, block, 0, stream>>>(h, u, v, out);
}